// Round 6
// baseline (562.953 us; speedup 1.0000x reference)
//
#include <hip/hip_runtime.h>
#include <hip/hip_bf16.h>
#include <math.h>

#define BATCH  8
#define NHEADS 8
#define KW     31
#define W      16384

// ---- workspace byte offsets ----
// floats at base: qWk [256][8] (2048 f), qWk_b [8], rpe_exp [8][31]
#define WS_QWKB 2048
#define WS_RPE  2056
#define OFF_WVH 9216                       // Wv bf16 [256][256]  (131072 B)
#define OFF_WOH (OFF_WVH + 131072)         // Wo bf16 [256][256]

typedef __attribute__((ext_vector_type(8))) short  short8;
typedef __attribute__((ext_vector_type(4))) float  f32x4;

__device__ __forceinline__ float f4c(const float4& v, int i) {
  switch (i) { case 0: return v.x; case 1: return v.y; case 2: return v.z; default: return v.w; }
}
__device__ __forceinline__ unsigned short f2bf(float f) {
  union { __hip_bfloat16 h; unsigned short u; } cv; cv.h = __float2bfloat16(f); return cv.u;
}
__device__ __forceinline__ float bf2f(unsigned short u) {
  union { __hip_bfloat16 h; unsigned short u; } cv; cv.u = u; return __bfloat162float(cv.h);
}

// ---------------------------------------------------------------- prep ------
// block 0: qWk [256][8], qWk_b[8], rpe_exp; blocks 1-4: Wv->bf16; 5-8: Wo->bf16
__global__ __launch_bounds__(256) void prep_kernel(
    const float* __restrict__ query, const float* __restrict__ Wk,
    const float* __restrict__ Wkb, const float* __restrict__ rpe,
    const float* __restrict__ Wv, const float* __restrict__ Wo,
    float* __restrict__ ws, unsigned short* __restrict__ WvH,
    unsigned short* __restrict__ WoH) {
  int t = threadIdx.x, bid = blockIdx.x;
  if (bid == 0) {
    __shared__ float q_l[256];
    float qv = query[t];
    float ss = qv * qv;
    #pragma unroll
    for (int m = 16; m >= 1; m >>= 1) ss += __shfl_xor(ss, m, 32);
    qv = qv / (sqrtf(ss) + 1e-6f) * 0.17677669529663687f;  // /(norm+1e-6)/sqrt(32)
    q_l[t] = qv;
    __syncthreads();
    const float* wr = Wk + (size_t)t * 256;
    #pragma unroll
    for (int h = 0; h < 8; ++h) {
      float s = 0.f;
      #pragma unroll
      for (int d = 0; d < 32; ++d) s = fmaf(q_l[h*32 + d], wr[h*32 + d], s);
      ws[t*8 + h] = s;
    }
    float pb = Wkb[t] * q_l[t];
    #pragma unroll
    for (int m = 16; m >= 1; m >>= 1) pb += __shfl_xor(pb, m, 32);
    if ((t & 31) == 0) ws[WS_QWKB + (t >> 5)] = pb;
    if (t < NHEADS * KW) ws[WS_RPE + t] = __expf(rpe[t]);
  } else {
    const float* src = (bid <= 4) ? Wv : Wo;
    unsigned short* dst = (bid <= 4) ? WvH : WoH;
    int seg = (bid - 1) & 3;
    int base4 = seg * 4096;   // float4 index base (16384 floats per segment)
    #pragma unroll
    for (int it = 0; it < 16; ++it) {
      int i4 = base4 + t + 256 * it;
      float4 v = ((const float4*)src)[i4];
      ushort4 o;
      o.x = f2bf(v.x); o.y = f2bf(v.y); o.z = f2bf(v.z); o.w = f2bf(v.w);
      ((ushort4*)dst)[i4] = o;
    }
  }
}

// -------------------------------------------------- fused whole-op kernel ---
// per (32-w output tile, batch): stage x[256][64w] (16-w halo each side),
// cost->ce (LDS), hi/lo bf16 split in place, MFMA1 v=Wv.x, vc=ce*(v+bias)
// into LDS (over dead x), conv K=31 + /sum_c -> u hi/lo (LDS), MFMA2
// out=Wo.u+bias, dense full-line stores. vc/ce/u never touch HBM.
// 1024 threads (16 waves), LDS 109.6 KB -> 1 block/CU (50% occupancy).
__global__ __launch_bounds__(1024, 4) void fused_kernel(
    const float* __restrict__ x, const float* __restrict__ wsf,
    const unsigned short* __restrict__ Av,   // WvH bf16 [256][256]
    const unsigned short* __restrict__ Ao,   // WoH bf16 [256][256]
    const float* __restrict__ biasv, const float* __restrict__ biaso,
    float* __restrict__ outp) {
  __shared__ __align__(16) float xs[64 * 260];   // 66,560 B  region A:
                                                 //  x fp32 -> x hi/lo bf16 -> vc fp32 -> outs fp32
  __shared__ __align__(16) float rgB[9216];      // 36,864 B  region B:
                                                 //  cbuf f32[1024][9] -> ubuf u16[32][528]
  __shared__ float ceL[512];                     // ce[8 h][64 s]
  __shared__ float rcl[256];                     // 1/sum_c [8 h][32 ow]
  __shared__ float rpel[256];                    // rpe_exp [8 h][32]
  __shared__ float bvL[256];
  __shared__ float boL[256];

  int t = threadIdx.x;
  int b = blockIdx.y;
  // XCD-chunked swizzle: 512 tiles -> 64 consecutive tiles per XCD (bijective)
  int tx = blockIdx.x;
  int tile = ((tx & 7) << 6) | (tx >> 3);
  int w0 = tile * 32;

  if (t < 256) {
    bvL[t] = biasv[t];
    boL[t] = biaso[t];
    int h = t >> 5, k = t & 31;
    rpel[t] = (k < KW) ? wsf[WS_RPE + h*KW + k] : 0.f;
  }

  // P1: load x[256 D][64 w] (gw = w0-16 .. w0+47), 4x4 transpose -> xs[w][D]
  {
    int tt = t & 255, db = t >> 8;         // db 0..3 (64-chan group)
    int rr = tt >> 4, c2 = tt & 15;
    int gwb = w0 - 16 + c2*4;              // aligned: float4 fully in or out
    const float* xb = x + ((size_t)b*256 + db*64 + rr*4)*W + gwb;
    float4 v0, v1, v2, v3;
    if (gwb >= 0 && gwb + 3 < W) {
      v0 = *(const float4*)(xb);
      v1 = *(const float4*)(xb + W);
      v2 = *(const float4*)(xb + 2*(size_t)W);
      v3 = *(const float4*)(xb + 3*(size_t)W);
    } else {
      v0 = v1 = v2 = v3 = make_float4(0.f, 0.f, 0.f, 0.f);
    }
    #pragma unroll
    for (int i = 0; i < 4; ++i) {
      float4 tv = make_float4(f4c(v0,i), f4c(v1,i), f4c(v2,i), f4c(v3,i));
      *(float4*)&xs[(c2*4 + i)*260 + db*64 + rr*4] = tv;
    }
  }
  __syncthreads();   // B0

  int w = t & 63, q = t >> 6;                  // wave-uniform q (0..15)
  int qu = __builtin_amdgcn_readfirstlane(q);

  // P2a: pull 16-chan run into regs, cost partials -> cbuf
  f32x4 xr[4];
  {
    const float* xrow = &xs[w*260 + qu*16];
    #pragma unroll
    for (int i = 0; i < 4; ++i) xr[i] = *(const f32x4*)(xrow + 4*i);
    float ca[8] = {0,0,0,0,0,0,0,0};
    const float* qr = wsf + (size_t)qu*128;    // qWk[D][8], D base qu*16
    #pragma unroll
    for (int k4 = 0; k4 < 4; ++k4)
      #pragma unroll
      for (int e = 0; e < 4; ++e)
        #pragma unroll
        for (int h = 0; h < 8; ++h)
          ca[h] = fmaf(xr[k4][e], qr[(k4*4 + e)*8 + h], ca[h]);
    #pragma unroll
    for (int h = 0; h < 8; ++h) rgB[t*9 + h] = ca[h];
  }
  __syncthreads();   // B1: xs fp32 reads done; cbuf visible

  // P2b: in-place hi/lo bf16 split (own 16 chans of row w)
  {
    unsigned short* hrow = (unsigned short*)xs + w*520 + qu*16;
    #pragma unroll
    for (int kc = 0; kc < 2; ++kc) {
      short8 hs, ls;
      #pragma unroll
      for (int e = 0; e < 4; ++e) {
        float a0 = xr[2*kc][e], a1 = xr[2*kc+1][e];
        unsigned short h0 = f2bf(a0), h1 = f2bf(a1);
        hs[e]   = (short)h0;  hs[e+4] = (short)h1;
        ls[e]   = (short)f2bf(a0 - bf2f(h0));
        ls[e+4] = (short)f2bf(a1 - bf2f(h1));
      }
      *(short8*)(hrow + 8*kc)       = hs;
      *(short8*)(hrow + 256 + 8*kc) = ls;
    }
  }
  // P3: reduce cost partials -> ceL (zero for OOB staged w)
  if (t < 512) {
    int h = t >> 6, s = t & 63;
    float sum = wsf[WS_QWKB + h];
    #pragma unroll
    for (int q2 = 0; q2 < 16; ++q2) sum += rgB[(q2*64 + s)*9 + h];
    int gw = w0 - 16 + s;
    ceL[h*64 + s] = (gw >= 0 && gw < W) ? __expf(sum) : 0.f;
  }
  __syncthreads();   // B2: hi/lo + ceL ready

  // rc = 1/sum_c (k ascending) — runs alongside MFMA1
  if (t < 256) {
    int h = t >> 5, ow = t & 31;
    float acc = 0.f;
    #pragma unroll
    for (int k = 0; k < KW; ++k) acc = fmaf(rpel[h*32 + k], ceL[h*64 + ow + 1 + k], acc);
    rcl[t] = 1.0f / acc;
  }

  // P4: MFMA1  v[256 o][64 w] = Wv . x (hi + lo); wave owns 16 o-rows
  int wid = t >> 6, quad = (t >> 4) & 3, m = t & 15;
  f32x4 acc1[4];
  #pragma unroll
  for (int c = 0; c < 4; ++c) acc1[c] = (f32x4){0.f, 0.f, 0.f, 0.f};
  {
    const unsigned short* xsu = (const unsigned short*)xs;
    #pragma unroll
    for (int kk = 0; kk < 8; ++kk) {
      int ko = kk*32 + quad*8;
      short8 a = *(const short8*)(Av + (size_t)(16*wid + m)*256 + ko);
      #pragma unroll
      for (int c = 0; c < 4; ++c) {
        short8 bh = *(const short8*)(xsu + (16*c + m)*520 + ko);
        short8 bl = *(const short8*)(xsu + (16*c + m)*520 + 256 + ko);
        acc1[c] = __builtin_amdgcn_mfma_f32_16x16x32_bf16(a, bh, acc1[c], 0, 0, 0);
        acc1[c] = __builtin_amdgcn_mfma_f32_16x16x32_bf16(a, bl, acc1[c], 0, 0, 0);
      }
    }
  }
  __syncthreads();   // B3: all xs B-reads done

  // P5: vc = ce * (v + bias) -> LDS over xs: vcl[s][256 o] pitch 260
  {
    int h = wid >> 1;                    // head of this wave's o-rows
    int ob = 16*wid + 4*quad;
    #pragma unroll
    for (int c = 0; c < 4; ++c) {
      int s = 16*c + m;
      float ce = ceL[h*64 + s];
      f32x4 r;
      #pragma unroll
      for (int i = 0; i < 4; ++i) r[i] = (acc1[c][i] + bvL[ob + i]) * ce;
      *(f32x4*)(xs + s*260 + ob) = r;
    }
  }
  __syncthreads();   // B4: vcl complete

  // P6: conv K=31, register sliding window; thread = 4 w x 4 chans.
  // Wave reads full contiguous 1 KB rows -> conflict-free.
  if (t < 512) {
    int g = t >> 6, pc = t & 63;         // w-group (4 out w), chan-quad
    int h = pc >> 3;
    float rp[KW];
    #pragma unroll
    for (int k = 0; k < KW; ++k) rp[k] = rpel[h*32 + k];
    f32x4 ac[4];
    #pragma unroll
    for (int j = 0; j < 4; ++j) ac[j] = (f32x4){0.f, 0.f, 0.f, 0.f};
    #pragma unroll
    for (int s = 0; s < 34; ++s) {
      f32x4 v = *(const f32x4*)(xs + (4*g + 1 + s)*260 + 4*pc);
      #pragma unroll
      for (int j = 0; j < 4; ++j) {
        int k = s - j;
        if (k >= 0 && k < KW) {
          #pragma unroll
          for (int e = 0; e < 4; ++e) ac[j][e] = fmaf(rp[k], v[e], ac[j][e]);
        }
      }
    }
    unsigned short* ubuf = (unsigned short*)rgB;   // [32 w][528]: hi|lo
    #pragma unroll
    for (int j = 0; j < 4; ++j) {
      int ow = 4*g + j;
      float rc = rcl[h*32 + ow];
      ushort4 hv, lv;
      #pragma unroll
      for (int e = 0; e < 4; ++e) {
        float u = ac[j][e] * rc;
        unsigned short hh = f2bf(u);
        ((unsigned short*)&hv)[e] = hh;
        ((unsigned short*)&lv)[e] = f2bf(u - bf2f(hh));
      }
      *(ushort4*)&ubuf[ow*528 + 4*pc]       = hv;
      *(ushort4*)&ubuf[ow*528 + 256 + 4*pc] = lv;
    }
  }
  __syncthreads();   // B5: ubuf complete, vcl reads done

  // P7: MFMA2  out[256 o][32 w] = Wo . u (hi then lo)
  f32x4 acc2[2];
  acc2[0] = (f32x4){0.f, 0.f, 0.f, 0.f};
  acc2[1] = (f32x4){0.f, 0.f, 0.f, 0.f};
  {
    const unsigned short* ubuf = (const unsigned short*)rgB;
    #pragma unroll
    for (int pass = 0; pass < 2; ++pass) {
      #pragma unroll
      for (int kk = 0; kk < 8; ++kk) {
        int ko = kk*32 + quad*8;
        short8 a = *(const short8*)(Ao + (size_t)(16*wid + m)*256 + ko);
        #pragma unroll
        for (int c = 0; c < 2; ++c) {
          short8 bv = *(const short8*)(ubuf + (16*c + m)*528 + pass*256 + ko);
          acc2[c] = __builtin_amdgcn_mfma_f32_16x16x32_bf16(a, bv, acc2[c], 0, 0, 0);
        }
      }
    }
  }
  // P8: assemble outs[256 o][32 w] over xs (vcl dead since B5)
  {
    float* outs = xs;
    int ob = 16*wid + 4*quad;
    #pragma unroll
    for (int c = 0; c < 2; ++c) {
      int ww = 16*c + m;
      #pragma unroll
      for (int i = 0; i < 4; ++i)
        outs[(ob + i)*32 + ww] = acc2[c][i] + boL[ob + i];
    }
  }
  __syncthreads();   // B6
  // P9: dense stores; per wave-instr 8 rows x 128 B full lines
  {
    const float* outs = xs;
    float* og = outp + (size_t)b*256*W + w0;
    #pragma unroll
    for (int it = 0; it < 2; ++it) {
      int idx = t + 1024*it;             // 2048 f32x4
      int o = idx >> 3, c4 = (idx & 7)*4;
      f32x4 v = *(const f32x4*)(outs + o*32 + c4);
      *(f32x4*)(og + (size_t)o*W + c4) = v;
    }
  }
}

// ---------------------------------------------------------------- launch ----
extern "C" void kernel_launch(void* const* d_in, const int* in_sizes, int n_in,
                              void* d_out, int out_size, void* d_ws, size_t ws_size,
                              hipStream_t stream) {
  const float* x     = (const float*)d_in[0];
  const float* query = (const float*)d_in[1];
  const float* Wk    = (const float*)d_in[2];
  const float* Wkb   = (const float*)d_in[3];
  const float* rpe   = (const float*)d_in[4];
  const float* Wv    = (const float*)d_in[5];
  const float* tvb   = (const float*)d_in[6];
  const float* Wo    = (const float*)d_in[7];
  const float* tob   = (const float*)d_in[8];
  float* out = (float*)d_out;
  char* wsb  = (char*)d_ws;
  float* wsf = (float*)d_ws;
  (void)in_sizes; (void)n_in; (void)out_size; (void)ws_size;

  unsigned short* WvH = (unsigned short*)(wsb + OFF_WVH);
  unsigned short* WoH = (unsigned short*)(wsb + OFF_WOH);

  prep_kernel<<<9, 256, 0, stream>>>(query, Wk, Wkb, rpe, Wv, Wo, wsf, WvH, WoH);
  fused_kernel<<<dim3(512, BATCH), 1024, 0, stream>>>(x, wsf, WvH, WoH, tvb, tob, out);
}